// Round 16
// baseline (14848.068 us; speedup 1.0000x reference)
//
#include <hip/hip_runtime.h>
#include <hip/hip_cooperative_groups.h>
#include <math.h>

#define LDEC 256
#define VOCD 34
#define SPIN_MAX 2000000u
#define XSTR 660   // LDS row stride (words): %32==20 -> 2-way bank aliasing (free)

typedef __attribute__((ext_vector_type(8))) short bf16x8;
typedef __attribute__((ext_vector_type(8))) unsigned short u16x8;
typedef __attribute__((ext_vector_type(4))) float f32x4;

// ---------------- workspace layout (byte offsets) ----------------
#define OFF_W1H  0u
#define OFF_W1L  2621440u
#define OFF_W2T  5242880u    // f32 [640 k][512 g]  (transposed, for VALU gates2)
#define OFF_EG   6553600u
#define OFF_B2   6832128u
#define OFF_WOT  6834176u
#define OFF_H1P  6868992u    // u32 [2][128 n][512 k]
#define OFF_H2P  7393280u    // f32 [128 n][128 u]  (fallback-only persistent h2)
#define OFF_CTXP 7524352u    // u32 [128 n][128 k]
#define OFF_C1   7589888u
#define OFF_C2   7852032u    // fallback-only
#define OFF_FLG  7917568u    // slot flags: A 8*32 slots, C 8*16 slots, 128B stride
#define OFF_KB   7966720u    // bf16 [512 t][128 n][128 k]
#define OFF_VB   24743936u
#define WS_NEED  41521152u

__device__ __forceinline__ float sigf(float x) { return 1.0f / (1.0f + expf(-x)); }
__device__ __forceinline__ unsigned short f2b(float x) {
  unsigned int u = __float_as_uint(x);
  unsigned int r = (u + 0x7FFFu + ((u >> 16) & 1u)) >> 16;
  return (unsigned short)r;
}
__device__ __forceinline__ float b2f(unsigned short h) {
  return __uint_as_float(((unsigned int)h) << 16);
}
__device__ __forceinline__ unsigned packf(float x) {
  unsigned short hi = f2b(x);
  unsigned short lo = f2b(x - b2f(hi));
  return ((unsigned)hi << 16) | (unsigned)lo;
}
__device__ __forceinline__ float unpackf(unsigned p) {
  return b2f((unsigned short)(p >> 16)) + b2f((unsigned short)(p & 0xffffu));
}
__device__ __forceinline__ unsigned aload(const unsigned* p) {
  return __hip_atomic_load((unsigned*)p, __ATOMIC_RELAXED, __HIP_MEMORY_SCOPE_SYSTEM);
}
__device__ __forceinline__ void astore(unsigned* p, unsigned v) {
  __hip_atomic_store(p, v, __ATOMIC_RELAXED, __HIP_MEMORY_SCOPE_SYSTEM);
}
__device__ __forceinline__ void unpack8(const unsigned* p, bf16x8& xh, bf16x8& xl) {
#pragma unroll
  for (int j = 0; j < 8; j++) {
    unsigned v = p[j];
    xh[j] = (short)(v >> 16);
    xl[j] = (short)(v & 0xffffu);
  }
}

// ---------------- pack kernels ----------------
__global__ __launch_bounds__(256) void pack_w1(const float* __restrict__ Wih1,
                                               const float* __restrict__ Whh1,
                                               unsigned short* __restrict__ W1H,
                                               unsigned short* __restrict__ W1L) {
  int idx = blockIdx.x * 256 + threadIdx.x;
  int m = idx / 640, k = idx % 640;
  int u = m >> 2, q = m & 3;
  int g = q * 512 + u;
  float v = (k < 128) ? Wih1[g * 384 + 256 + k] : Whh1[g * 512 + (k - 128)];
  unsigned short hi = f2b(v);
  W1H[idx] = hi;
  W1L[idx] = f2b(v - b2f(hi));
}

__global__ __launch_bounds__(256) void pack_w2t(const float* __restrict__ Wih2,
                                                const float* __restrict__ Whh2,
                                                float* __restrict__ W2T) {
  int idx = blockIdx.x * 256 + threadIdx.x;    // < 640*512
  int k = idx >> 9, g = idx & 511;
  W2T[idx] = (k < 512) ? Wih2[g * 512 + k] : Whh2[g * 128 + (k - 512)];
}

__global__ __launch_bounds__(256) void pack_eg(const float* __restrict__ emb,
                                               const float* __restrict__ Wih1,
                                               const float* __restrict__ bih1,
                                               const float* __restrict__ bhh1,
                                               float* __restrict__ EG) {
  int idx = blockIdx.x * 256 + threadIdx.x;
  int v = idx >> 11, m = idx & 2047;
  int u = m >> 2, q = m & 3;
  int g = q * 512 + u;
  float acc = bih1[g] + bhh1[g];
  const float* e = emb + v * 256;
  const float* w = Wih1 + g * 384;
  for (int k = 0; k < 256; k++) acc += e[k] * w[k];
  EG[idx] = acc;
}

__global__ __launch_bounds__(256) void pack_misc(const float* __restrict__ Wout,
                                                 const float* __restrict__ bih2,
                                                 const float* __restrict__ bhh2,
                                                 float* __restrict__ WoT,
                                                 float* __restrict__ B2) {
  int idx = blockIdx.x * 256 + threadIdx.x;
  if (idx < 8704) {
    int k = idx / 34, v = idx % 34;
    WoT[idx] = Wout[v * 256 + k];
  } else if (idx < 9216) {
    int m = idx - 8704;
    int u = m >> 2, q = m & 3;
    int g = q * 128 + u;
    B2[m] = bih2[g] + bhh2[g];
  }
}

__global__ __launch_bounds__(256) void pack_kv(const float* __restrict__ key,
                                               const float* __restrict__ values,
                                               unsigned short* __restrict__ KB,
                                               unsigned short* __restrict__ VB) {
  size_t idx = (size_t)blockIdx.x * 256 + threadIdx.x;
  KB[idx] = f2b(key[idx]);
  VB[idx] = f2b(values[idx]);
}

// ================= staging helpers (stride XSTR) =================
__device__ __forceinline__ void stage_h1(int gang, int tid, int rbuf,
                                         unsigned* xshA, const unsigned* __restrict__ H1P) {
  int kcol = tid & 15, nl = (tid >> 4) & 15, rep = tid >> 8;
  int n = gang * 16 + nl;
  const unsigned* h1p = H1P + rbuf * 65536 + n * 512;
#pragma unroll
  for (int j = 0; j < 10; j++) {
    int k = rep * 160 + j * 16 + kcol;
    if (k >= 128) xshA[nl * XSTR + k] = aload(h1p + (k - 128));
  }
}
__device__ __forceinline__ void stage_ctx(int gang, int tid,
                                          unsigned* xshA, const unsigned* __restrict__ CTXP) {
  int kcol = tid & 15, nl = (tid >> 4) & 15, rep = tid >> 8;
  int n = gang * 16 + nl;
  if (rep == 0) {
#pragma unroll
    for (int j = 0; j < 8; j++) {
      int k = j * 16 + kcol;
      xshA[nl * XSTR + k] = aload(CTXP + n * 128 + k);
    }
  }
}

// ================= phase A (R12-validated MFMA) =================
__device__ __forceinline__ void A_compute(
    int gang, int gidx, int tid, int t, int wp,
    const unsigned* __restrict__ xshA, float* bred,
    const unsigned short* __restrict__ W1H, const unsigned short* __restrict__ W1L,
    const float* __restrict__ EG, const int* __restrict__ text,
    unsigned* __restrict__ H1P, float* __restrict__ C1)
{
  const int wid = tid >> 6, lane = tid & 63;
  const int l15 = lane & 15, lg = lane >> 4;
  const int gr = wid >> 2, gwid = wid & 3;
  const int kb0 = gwid * 160;
  const int mt = gidx * 4 + gr;

  {
    const unsigned short* whp = W1H + (size_t)(mt * 16 + l15) * 640 + kb0 + lg * 8;
    const unsigned short* wlp = W1L + (size_t)(mt * 16 + l15) * 640 + kb0 + lg * 8;
    const unsigned* xrow = xshA + l15 * XSTR + kb0 + lg * 8;
    f32x4 a0 = {0.0f, 0.0f, 0.0f, 0.0f};
    f32x4 a1 = {0.0f, 0.0f, 0.0f, 0.0f};
    f32x4 a2 = {0.0f, 0.0f, 0.0f, 0.0f};
#pragma unroll
    for (int ks = 0; ks < 5; ks++) {
      unsigned parr[8];
      *(uint4*)parr       = *(const uint4*)(xrow + ks * 32);
      *(uint4*)(parr + 4) = *(const uint4*)(xrow + ks * 32 + 4);
      bf16x8 xh_, xl_;
      unpack8(parr, xh_, xl_);
      bf16x8 wh_ = *(const bf16x8*)(whp + ks * 32);
      bf16x8 wl_ = *(const bf16x8*)(wlp + ks * 32);
      a0 = __builtin_amdgcn_mfma_f32_16x16x32_bf16(wh_, xh_, a0, 0, 0, 0);
      a1 = __builtin_amdgcn_mfma_f32_16x16x32_bf16(wl_, xh_, a1, 0, 0, 0);
      a2 = __builtin_amdgcn_mfma_f32_16x16x32_bf16(wh_, xl_, a2, 0, 0, 0);
    }
    f32x4 acc = a0 + a1;
    acc = acc + a2;
#pragma unroll
    for (int q = 0; q < 4; q++) bred[gr * 1024 + q * 256 + gwid * 64 + lane] = acc[q];
  }
  __syncthreads();

  if (gwid == 0) {
    const float* br = bred + gr * 1024;
    int n = gang * 16 + l15;
    int tok = text[n * LDEC + t];
    f32x4 egv = *(const f32x4*)(EG + (size_t)tok * 2048 + mt * 16 + lg * 4);
    float g0 = br[lane]       + br[64 + lane]  + br[128 + lane] + br[192 + lane] + egv[0];
    float g1 = br[256 + lane] + br[320 + lane] + br[384 + lane] + br[448 + lane] + egv[1];
    float g2 = br[512 + lane] + br[576 + lane] + br[640 + lane] + br[704 + lane] + egv[2];
    float g3 = br[768 + lane] + br[832 + lane] + br[896 + lane] + br[960 + lane] + egv[3];
    float ig = sigf(g0), fg = sigf(g1), gg = tanhf(g2), og = sigf(g3);
    int u = mt * 4 + lg;
    float c = fg * C1[u * 128 + n] + ig * gg;
    float h = og * tanhf(c);
    C1[u * 128 + n] = c;
    astore(H1P + wp * 65536 + n * 512 + u, packf(h));
  }
  __syncthreads();
}

// ================= phase C2: gates2 (fp32 VALU) + LSTM2 + attention =================
// h1 comes from xshA row `nl`; h2old/c2 live in LDS (h2olds/c2s).
template <int BF16KV>
__device__ __forceinline__ void C2_compute(
    int n, int nl, int tid, int len, int t,
    const unsigned* __restrict__ xshA,
    float* gred, float* cred, float* es, float* ctxs, float* pr, float* sred,
    float* h2olds, float* c2s,
    const float* __restrict__ W2T, const float* __restrict__ B2,
    const float* __restrict__ key, const float* __restrict__ values,
    const unsigned short* __restrict__ KB, const unsigned short* __restrict__ VB,
    const float* __restrict__ WoT, const float* __restrict__ bout,
    unsigned* __restrict__ CTXP, float* __restrict__ out)
{
  const int wid = tid >> 6, lane = tid & 63;

  // ---- gates2: 512 g x 640 k fp32 GEMV, 2-way k-split ----
  {
    const unsigned* xrow = xshA + nl * XSTR;
    int g = tid & 511, half = tid >> 9;
    const float* wcol = W2T + (size_t)(half * 320) * 512 + g;
    float acc = 0.0f;
#pragma unroll 8
    for (int k = 0; k < 320; k++) {
      int kk = half * 320 + k;
      float xv = (kk < 512) ? unpackf(xrow[128 + kk]) : h2olds[kk - 512];
      acc += wcol[(size_t)k * 512] * xv;
    }
    gred[tid] = acc;
  }
  __syncthreads();
  if (tid < 128) {
    int u = tid;
    f32x4 bq = *(const f32x4*)(B2 + u * 4);
    float g0 = gred[u]       + gred[512 + u]       + bq[0];
    float g1 = gred[128 + u] + gred[640 + u]       + bq[1];
    float g2 = gred[256 + u] + gred[768 + u]       + bq[2];
    float g3 = gred[384 + u] + gred[896 + u]       + bq[3];
    float c = sigf(g1) * c2s[u] + sigf(g0) * tanhf(g2);
    float h = sigf(g3) * tanhf(c);
    c2s[u] = c;
    h2olds[u] = h;     // h2(t): used by attention below and next step's gates2
  }
  __syncthreads();

  // ---- attention (R15-validated: fixed-shift softmax, shfl sums) ----
  float ls = 0.0f;
  if (tid < len) {
    float acc = 0.0f;
    if (BF16KV) {
      const u16x8* kr = (const u16x8*)(KB + ((size_t)tid * 128 + n) * 128);
#pragma unroll 4
      for (int k = 0; k < 16; k++) {
        u16x8 kv = kr[k];
#pragma unroll
        for (int j = 0; j < 8; j++) acc += b2f(kv[j]) * h2olds[k * 8 + j];
      }
    } else {
      const float4* kr = (const float4*)(key + ((size_t)tid * 128 + n) * 128);
#pragma unroll 8
      for (int k = 0; k < 32; k++) {
        float4 kv = kr[k];
        acc += kv.x * h2olds[4 * k] + kv.y * h2olds[4 * k + 1]
             + kv.z * h2olds[4 * k + 2] + kv.w * h2olds[4 * k + 3];
      }
    }
    float p = expf(acc - 20.0f);   // fixed shift: exact softmax
    es[tid] = p;
    ls = p;
  }
  ls += __shfl_xor(ls, 32); ls += __shfl_xor(ls, 16); ls += __shfl_xor(ls, 8);
  ls += __shfl_xor(ls, 4);  ls += __shfl_xor(ls, 2);  ls += __shfl_xor(ls, 1);
  if (lane == 0) sred[wid] = ls;
  __syncthreads();
  float S = 0.0f;
#pragma unroll
  for (int w = 0; w < 16; w++) S += sred[w];
  {
    int v4 = (tid & 31) * 4, tp = tid >> 5;
    float ax = 0.0f, ay = 0.0f, az = 0.0f, aw = 0.0f;
    if (BF16KV) {
#pragma unroll 2
      for (int tt = tp; tt < len; tt += 32) {
        float p = es[tt];
        const unsigned* w = (const unsigned*)(VB + ((size_t)tt * 128 + n) * 128 + v4);
        unsigned w0 = w[0], w1 = w[1];
        ax += p * b2f((unsigned short)(w0 & 0xffffu));
        ay += p * b2f((unsigned short)(w0 >> 16));
        az += p * b2f((unsigned short)(w1 & 0xffffu));
        aw += p * b2f((unsigned short)(w1 >> 16));
      }
    } else {
#pragma unroll 2
      for (int tt = tp; tt < len; tt += 32) {
        float p = es[tt];
        const float4 vv = *(const float4*)(values + ((size_t)tt * 128 + n) * 128 + v4);
        ax += p * vv.x; ay += p * vv.y; az += p * vv.z; aw += p * vv.w;
      }
    }
    float4 a4 = {ax, ay, az, aw};
    *(float4*)&cred[tp * 132 + v4] = a4;
  }
  __syncthreads();
  if (tid < 128) {
    float s4 = 0.0f;
#pragma unroll 8
    for (int tp2 = 0; tp2 < 32; tp2++) s4 += cred[tp2 * 132 + tid];
    float cv = s4 / S;
    ctxs[tid] = cv;
    astore(CTXP + n * 128 + tid, packf(cv));
  }
  __syncthreads();
  if (tid < 68) {
    int vv = tid % 34, part = tid / 34;
    const float* src = part ? ctxs : h2olds;
    const float* wcol = WoT + (part ? 128 * 34 : 0);
    float a = 0.0f;
#pragma unroll 8
    for (int k2 = 0; k2 < 128; k2++) a += src[k2] * wcol[k2 * 34 + vv];
    pr[tid] = a;
  }
  __syncthreads();
  if (tid < 34) {
    out[(size_t)n * (LDEC * VOCD) + t * VOCD + tid] = bout[tid] + pr[tid] + pr[34 + tid];
  }
  __syncthreads();
}

// ---------------- standalone fallback kernels ----------------
__global__ void __launch_bounds__(1024, 1) kA(
    const unsigned short* __restrict__ W1H, const unsigned short* __restrict__ W1L,
    const float* __restrict__ EG, const int* __restrict__ text,
    const unsigned* __restrict__ CTXP, unsigned* __restrict__ H1P,
    float* __restrict__ C1, int t, int rp, int wp)
{
  __shared__ unsigned xshA[16 * XSTR];
  __shared__ float bred[4096];
  const int gang = blockIdx.x >> 5, gidx = blockIdx.x & 31;
  stage_h1(gang, threadIdx.x, rp, xshA, H1P);
  stage_ctx(gang, threadIdx.x, xshA, CTXP);
  __syncthreads();
  A_compute(gang, gidx, threadIdx.x, t, wp, xshA, bred, W1H, W1L, EG, text, H1P, C1);
}

template <int BF16KV>
__global__ void __launch_bounds__(1024, 1) kC2(
    const float* __restrict__ key, const float* __restrict__ values,
    const unsigned short* __restrict__ KB, const unsigned short* __restrict__ VB,
    const int* __restrict__ lens,
    const float* __restrict__ W2T, const float* __restrict__ B2,
    const float* __restrict__ WoT, const float* __restrict__ bout,
    const unsigned* __restrict__ H1P, float* __restrict__ H2F, float* __restrict__ C2,
    unsigned* __restrict__ CTXP, float* __restrict__ out, int t, int wp)
{
  __shared__ unsigned xsh1[16 * XSTR];   // only row 0 used (h1 of this n)
  __shared__ float gred[1024];
  __shared__ float cred[4224];
  __shared__ float es[512];
  __shared__ float ctxs[128];
  __shared__ float pr[68];
  __shared__ float sred[16];
  __shared__ float h2olds[128];
  __shared__ float c2s[128];
  const int n = blockIdx.x, tid = threadIdx.x;
  if (tid < 512) xsh1[128 + tid] = aload(H1P + wp * 65536 + n * 512 + tid);
  if (tid < 128) { h2olds[tid] = H2F[n * 128 + tid]; c2s[tid] = C2[n * 128 + tid]; }
  __syncthreads();
  C2_compute<BF16KV>(n, 0, tid, lens[n], t, xsh1, gred, cred, es, ctxs, pr, sred,
                     h2olds, c2s, W2T, B2, key, values, KB, VB, WoT, bout, CTXP, out);
  if (tid < 128) { H2F[n * 128 + tid] = h2olds[tid]; C2[n * 128 + tid] = c2s[tid]; }
}

// ---------------- persistent gang kernel: 2 slot-flag hops per step ----------------
template <int BF16KV>
__global__ void __launch_bounds__(1024, 1) decoder_coop(
    const float* __restrict__ key, const float* __restrict__ values,
    const unsigned short* __restrict__ KB, const unsigned short* __restrict__ VB,
    const int* __restrict__ lens, const int* __restrict__ text,
    const float* __restrict__ EG, const float* __restrict__ B2,
    const float* __restrict__ WoT, const float* __restrict__ bout,
    const unsigned short* __restrict__ W1H, const unsigned short* __restrict__ W1L,
    const float* __restrict__ W2T,
    unsigned* __restrict__ CTXP, unsigned* __restrict__ H1P,
    float* __restrict__ C1, unsigned* __restrict__ FLG, float* __restrict__ out)
{
  __shared__ unsigned xshA[16 * XSTR];
  __shared__ float bred[4096];
  __shared__ float gred[1024];
  __shared__ float cred[4224];
  __shared__ float es[512];
  __shared__ float ctxs[128];
  __shared__ float pr[68];
  __shared__ float sred[16];
  __shared__ float h2olds[128];
  __shared__ float c2s[128];
  __shared__ unsigned deadsh;

  const int bid = blockIdx.x, tid = threadIdx.x;
  const int gang = bid >> 5, gidx = bid & 31;
  unsigned* sA = FLG + gang * 1024;          // 32 slots x 32 words
  unsigned* sC = FLG + 8192 + gang * 512;    // 16 slots x 32 words
  const int cn = gang * 16 + gidx;
  const int clen = (gidx < 16) ? lens[cn] : 0;

  unsigned budget = SPIN_MAX;

  if (tid < 128) { h2olds[tid] = 0.0f; c2s[tid] = 0.0f; }
  if (tid == 0) deadsh = 0u;
  stage_h1(gang, tid, 1, xshA, H1P);     // h1(-1)=0 (buf1 zeroed)
  __syncthreads();

  for (int t = 0; t < LDEC; t++) {
    const int wp = t & 1;
    const unsigned tv = (unsigned)(t + 1);

    // ---- A: ctx stage + MFMA gates1 + LSTM1 ----
    stage_ctx(gang, tid, xshA, CTXP);
    __syncthreads();
    A_compute(gang, gidx, tid, t, wp, xshA, bred, W1H, W1L, EG, text, H1P, C1);
    if (tid == 0) {
      __builtin_amdgcn_s_waitcnt(0);
      astore(sA + gidx * 32, tv);
    }
    // wait all 32 A slots (parallel per-slot polling, no RMW contention)
    if (tid < 32) {
      unsigned* s = sA + tid * 32;
      while (budget && aload(s) < tv) {
        __builtin_amdgcn_s_sleep(1);
        if (--budget == 0) deadsh = 1u;
      }
    }
    __syncthreads();

    // ---- prestage h1(t) for next A and for C's gates2 ----
    stage_h1(gang, tid, wp, xshA, H1P);
    __syncthreads();

    // ---- C (blocks gidx<16): gates2 + LSTM2 + attention + proj ----
    if (gidx < 16) {
      C2_compute<BF16KV>(cn, gidx, tid, clen, t, xshA, gred, cred, es, ctxs, pr,
                         sred, h2olds, c2s, W2T, B2, key, values, KB, VB,
                         WoT, bout, CTXP, out);
      if (tid == 0) {
        __builtin_amdgcn_s_waitcnt(0);
        astore(sC + gidx * 32, tv);
      }
    }
    // wait all 16 C slots
    if (tid < 16) {
      unsigned* s = sC + tid * 32;
      while (budget && aload(s) < tv) {
        __builtin_amdgcn_s_sleep(1);
        if (--budget == 0) deadsh = 1u;
      }
    }
    __syncthreads();
  }

  if (tid == 0 && deadsh) out[0] = 7.0e6f;
}

extern "C" void kernel_launch(void* const* d_in, const int* in_sizes, int n_in,
                              void* d_out, int out_size, void* d_ws, size_t ws_size,
                              hipStream_t stream) {
  const float* key    = (const float*)d_in[0];
  const float* values = (const float*)d_in[1];
  const int*   lens   = (const int*)d_in[2];
  const int*   text   = (const int*)d_in[3];
  const float* emb    = (const float*)d_in[4];
  const float* Wih1   = (const float*)d_in[5];
  const float* Whh1   = (const float*)d_in[6];
  const float* bih1   = (const float*)d_in[7];
  const float* bhh1   = (const float*)d_in[8];
  const float* Wih2   = (const float*)d_in[9];
  const float* Whh2   = (const float*)d_in[10];
  const float* bih2   = (const float*)d_in[11];
  const float* bhh2   = (const float*)d_in[12];
  const float* Wout   = (const float*)d_in[13];
  const float* bout   = (const float*)d_in[14];

  char* ws = (char*)d_ws;
  unsigned short* W1H = (unsigned short*)(ws + OFF_W1H);
  unsigned short* W1L = (unsigned short*)(ws + OFF_W1L);
  float* W2T  = (float*)(ws + OFF_W2T);
  float* EG   = (float*)(ws + OFF_EG);
  float* B2   = (float*)(ws + OFF_B2);
  float* WoT  = (float*)(ws + OFF_WOT);
  unsigned* H1P  = (unsigned*)(ws + OFF_H1P);
  float* H2F  = (float*)(ws + OFF_H2P);
  unsigned* CTXP = (unsigned*)(ws + OFF_CTXP);
  float* C1   = (float*)(ws + OFF_C1);
  float* C2   = (float*)(ws + OFF_C2);
  unsigned* FLG = (unsigned*)(ws + OFF_FLG);
  unsigned short* KB = (unsigned short*)(ws + OFF_KB);
  unsigned short* VB = (unsigned short*)(ws + OFF_VB);
  float* out  = (float*)d_out;

  const bool use16 = (ws_size >= (size_t)WS_NEED);

  hipMemsetAsync(CTXP, 0, 65536, stream);
  hipMemsetAsync((char*)H1P + 262144, 0, 262144, stream);   // buf1: h1(-1)=0
  hipMemsetAsync(H2F, 0, 65536, stream);                    // fallback h2(-1)=0
  hipMemsetAsync(C1,  0, 262144, stream);
  hipMemsetAsync(C2,  0, 65536, stream);
  hipMemsetAsync(FLG, 0, 49152, stream);

  pack_w1  <<<5120, 256, 0, stream>>>(Wih1, Whh1, W1H, W1L);
  pack_w2t <<<1280, 256, 0, stream>>>(Wih2, Whh2, W2T);
  pack_eg  <<<272,  256, 0, stream>>>(emb, Wih1, bih1, bhh1, EG);
  pack_misc<<<36,   256, 0, stream>>>(Wout, bih2, bhh2, WoT, B2);
  if (use16) pack_kv<<<32768, 256, 0, stream>>>(key, values, KB, VB);

  const void* coop_fn = use16 ? (const void*)decoder_coop<1>
                              : (const void*)decoder_coop<0>;

  int maxBlk = 0;
  hipError_t qerr = hipOccupancyMaxActiveBlocksPerMultiprocessor(
      &maxBlk, coop_fn, 1024, 0);
  bool coop_ok = (qerr == hipSuccess && maxBlk >= 1);

  if (coop_ok) {
    void* args[] = {
      (void*)&key, (void*)&values, (void*)&KB, (void*)&VB,
      (void*)&lens, (void*)&text,
      (void*)&EG, (void*)&B2, (void*)&WoT, (void*)&bout,
      (void*)&W1H, (void*)&W1L, (void*)&W2T,
      (void*)&CTXP, (void*)&H1P, (void*)&C1, (void*)&FLG, (void*)&out
    };
    hipError_t err = hipLaunchCooperativeKernel(coop_fn, dim3(256), dim3(1024),
                                                args, 0, stream);
    if (err == hipSuccess) return;
  }

  // fallback: multi-launch (kernel boundaries provide sync/visibility)
  for (int t = 0; t < LDEC; t++) {
    const int wp = t & 1, rp = (t + 1) & 1;
    kA<<<256, 1024, 0, stream>>>(W1H, W1L, EG, text, CTXP, H1P, C1, t, rp, wp);
    if (use16)
      kC2<1><<<128, 1024, 0, stream>>>(key, values, KB, VB, lens, W2T, B2, WoT, bout,
                                       H1P, H2F, C2, CTXP, out, t, wp);
    else
      kC2<0><<<128, 1024, 0, stream>>>(key, values, KB, VB, lens, W2T, B2, WoT, bout,
                                       H1P, H2F, C2, CTXP, out, t, wp);
  }
}

// Round 17
// 7875.370 us; speedup vs baseline: 1.8854x; 1.8854x over previous
//
#include <hip/hip_runtime.h>
#include <hip/hip_cooperative_groups.h>
#include <math.h>

#define LDEC 256
#define VOCD 34
#define SPIN_MAX 2000000u
#define XSTR 660   // LDS row stride (words): %32==20 -> 2-way bank aliasing (free)

typedef __attribute__((ext_vector_type(8))) short bf16x8;
typedef __attribute__((ext_vector_type(8))) unsigned short u16x8;
typedef __attribute__((ext_vector_type(4))) float f32x4;

// ---------------- workspace layout (byte offsets) ----------------
#define OFF_W1H  0u
#define OFF_W1L  2621440u
#define OFF_W2H  5242880u
#define OFF_W2L  5898240u
#define OFF_EG   6553600u
#define OFF_B2   6832128u
#define OFF_WOT  6834176u
#define OFF_H1P  6868992u    // u32 [2][128 n][512 k]
#define OFF_H2P  7393280u    // u32 [2][128 n][128 u]
#define OFF_CTXP 7524352u    // u32 [128 n][128 k]
#define OFF_C1   7589888u
#define OFF_C2   7852032u
#define OFF_FLG  7917568u    // slot flags: sA 8g*32, sB 8g*32, sC 8g*16; 64B stride
#define OFF_KB   7966720u    // bf16 [512 t][128 n][128 k]
#define OFF_VB   24743936u
#define WS_NEED  41521152u

__device__ __forceinline__ float sigf(float x) { return 1.0f / (1.0f + expf(-x)); }
__device__ __forceinline__ unsigned short f2b(float x) {
  unsigned int u = __float_as_uint(x);
  unsigned int r = (u + 0x7FFFu + ((u >> 16) & 1u)) >> 16;
  return (unsigned short)r;
}
__device__ __forceinline__ float b2f(unsigned short h) {
  return __uint_as_float(((unsigned int)h) << 16);
}
__device__ __forceinline__ unsigned packf(float x) {
  unsigned short hi = f2b(x);
  unsigned short lo = f2b(x - b2f(hi));
  return ((unsigned)hi << 16) | (unsigned)lo;
}
__device__ __forceinline__ float unpackf(unsigned p) {
  return b2f((unsigned short)(p >> 16)) + b2f((unsigned short)(p & 0xffffu));
}
__device__ __forceinline__ unsigned aload(const unsigned* p) {
  return __hip_atomic_load((unsigned*)p, __ATOMIC_RELAXED, __HIP_MEMORY_SCOPE_SYSTEM);
}
__device__ __forceinline__ void astore(unsigned* p, unsigned v) {
  __hip_atomic_store(p, v, __ATOMIC_RELAXED, __HIP_MEMORY_SCOPE_SYSTEM);
}
__device__ __forceinline__ void unpack8(const unsigned* p, bf16x8& xh, bf16x8& xl) {
#pragma unroll
  for (int j = 0; j < 8; j++) {
    unsigned v = p[j];
    xh[j] = (short)(v >> 16);
    xl[j] = (short)(v & 0xffffu);
  }
}

// ---------------- pack kernels ----------------
__global__ __launch_bounds__(256) void pack_w1(const float* __restrict__ Wih1,
                                               const float* __restrict__ Whh1,
                                               unsigned short* __restrict__ W1H,
                                               unsigned short* __restrict__ W1L) {
  int idx = blockIdx.x * 256 + threadIdx.x;
  int m = idx / 640, k = idx % 640;
  int u = m >> 2, q = m & 3;
  int g = q * 512 + u;
  float v = (k < 128) ? Wih1[g * 384 + 256 + k] : Whh1[g * 512 + (k - 128)];
  unsigned short hi = f2b(v);
  W1H[idx] = hi;
  W1L[idx] = f2b(v - b2f(hi));
}

__global__ __launch_bounds__(256) void pack_w2(const float* __restrict__ Wih2,
                                               const float* __restrict__ Whh2,
                                               unsigned short* __restrict__ W2H,
                                               unsigned short* __restrict__ W2L) {
  int idx = blockIdx.x * 256 + threadIdx.x;
  int m = idx / 640, k = idx % 640;
  int u = m >> 2, q = m & 3;
  int g = q * 128 + u;
  float v = (k < 512) ? Wih2[g * 512 + k] : Whh2[g * 128 + (k - 512)];
  unsigned short hi = f2b(v);
  W2H[idx] = hi;
  W2L[idx] = f2b(v - b2f(hi));
}

__global__ __launch_bounds__(256) void pack_eg(const float* __restrict__ emb,
                                               const float* __restrict__ Wih1,
                                               const float* __restrict__ bih1,
                                               const float* __restrict__ bhh1,
                                               float* __restrict__ EG) {
  int idx = blockIdx.x * 256 + threadIdx.x;
  int v = idx >> 11, m = idx & 2047;
  int u = m >> 2, q = m & 3;
  int g = q * 512 + u;
  float acc = bih1[g] + bhh1[g];
  const float* e = emb + v * 256;
  const float* w = Wih1 + g * 384;
  for (int k = 0; k < 256; k++) acc += e[k] * w[k];
  EG[idx] = acc;
}

__global__ __launch_bounds__(256) void pack_misc(const float* __restrict__ Wout,
                                                 const float* __restrict__ bih2,
                                                 const float* __restrict__ bhh2,
                                                 float* __restrict__ WoT,
                                                 float* __restrict__ B2) {
  int idx = blockIdx.x * 256 + threadIdx.x;
  if (idx < 8704) {
    int k = idx / 34, v = idx % 34;
    WoT[idx] = Wout[v * 256 + k];
  } else if (idx < 9216) {
    int m = idx - 8704;
    int u = m >> 2, q = m & 3;
    int g = q * 128 + u;
    B2[m] = bih2[g] + bhh2[g];
  }
}

__global__ __launch_bounds__(256) void pack_kv(const float* __restrict__ key,
                                               const float* __restrict__ values,
                                               unsigned short* __restrict__ KB,
                                               unsigned short* __restrict__ VB) {
  size_t idx = (size_t)blockIdx.x * 256 + threadIdx.x;
  KB[idx] = f2b(key[idx]);
  VB[idx] = f2b(values[idx]);
}

// ================= staging helpers (stride XSTR) =================
__device__ __forceinline__ void stage_h1(int gang, int tid, int rbuf,
                                         unsigned* xshA, const unsigned* __restrict__ H1P) {
  int kcol = tid & 15, nl = (tid >> 4) & 15, rep = tid >> 8;
  int n = gang * 16 + nl;
  const unsigned* h1p = H1P + rbuf * 65536 + n * 512;
#pragma unroll
  for (int j = 0; j < 10; j++) {
    int k = rep * 160 + j * 16 + kcol;
    if (k >= 128) xshA[nl * XSTR + k] = aload(h1p + (k - 128));
  }
}
__device__ __forceinline__ void stage_ctx(int gang, int tid,
                                          unsigned* xshA, const unsigned* __restrict__ CTXP) {
  int kcol = tid & 15, nl = (tid >> 4) & 15, rep = tid >> 8;
  int n = gang * 16 + nl;
  if (rep == 0) {
#pragma unroll
    for (int j = 0; j < 8; j++) {
      int k = j * 16 + kcol;
      xshA[nl * XSTR + k] = aload(CTXP + n * 128 + k);
    }
  }
}

// ================= phase A (R12-validated MFMA) =================
__device__ __forceinline__ void A_compute(
    int gang, int gidx, int tid, int t, int wp,
    const unsigned* __restrict__ xshA, float* bred,
    const unsigned short* __restrict__ W1H, const unsigned short* __restrict__ W1L,
    const float* __restrict__ EG, const int* __restrict__ text,
    unsigned* __restrict__ H1P, float* __restrict__ C1)
{
  const int wid = tid >> 6, lane = tid & 63;
  const int l15 = lane & 15, lg = lane >> 4;
  const int gr = wid >> 2, gwid = wid & 3;
  const int kb0 = gwid * 160;
  const int mt = gidx * 4 + gr;

  {
    const unsigned short* whp = W1H + (size_t)(mt * 16 + l15) * 640 + kb0 + lg * 8;
    const unsigned short* wlp = W1L + (size_t)(mt * 16 + l15) * 640 + kb0 + lg * 8;
    const unsigned* xrow = xshA + l15 * XSTR + kb0 + lg * 8;
    f32x4 a0 = {0.0f, 0.0f, 0.0f, 0.0f};
    f32x4 a1 = {0.0f, 0.0f, 0.0f, 0.0f};
    f32x4 a2 = {0.0f, 0.0f, 0.0f, 0.0f};
#pragma unroll
    for (int ks = 0; ks < 5; ks++) {
      unsigned parr[8];
      *(uint4*)parr       = *(const uint4*)(xrow + ks * 32);
      *(uint4*)(parr + 4) = *(const uint4*)(xrow + ks * 32 + 4);
      bf16x8 xh_, xl_;
      unpack8(parr, xh_, xl_);
      bf16x8 wh_ = *(const bf16x8*)(whp + ks * 32);
      bf16x8 wl_ = *(const bf16x8*)(wlp + ks * 32);
      a0 = __builtin_amdgcn_mfma_f32_16x16x32_bf16(wh_, xh_, a0, 0, 0, 0);
      a1 = __builtin_amdgcn_mfma_f32_16x16x32_bf16(wl_, xh_, a1, 0, 0, 0);
      a2 = __builtin_amdgcn_mfma_f32_16x16x32_bf16(wh_, xl_, a2, 0, 0, 0);
    }
    f32x4 acc = a0 + a1;
    acc = acc + a2;
#pragma unroll
    for (int q = 0; q < 4; q++) bred[gr * 1024 + q * 256 + gwid * 64 + lane] = acc[q];
  }
  __syncthreads();

  if (gwid == 0) {
    const float* br = bred + gr * 1024;
    int n = gang * 16 + l15;
    int tok = text[n * LDEC + t];
    f32x4 egv = *(const f32x4*)(EG + (size_t)tok * 2048 + mt * 16 + lg * 4);
    float g0 = br[lane]       + br[64 + lane]  + br[128 + lane] + br[192 + lane] + egv[0];
    float g1 = br[256 + lane] + br[320 + lane] + br[384 + lane] + br[448 + lane] + egv[1];
    float g2 = br[512 + lane] + br[576 + lane] + br[640 + lane] + br[704 + lane] + egv[2];
    float g3 = br[768 + lane] + br[832 + lane] + br[896 + lane] + br[960 + lane] + egv[3];
    float ig = sigf(g0), fg = sigf(g1), gg = tanhf(g2), og = sigf(g3);
    int u = mt * 4 + lg;
    float c = fg * C1[u * 128 + n] + ig * gg;
    float h = og * tanhf(c);
    C1[u * 128 + n] = c;
    astore(H1P + wp * 65536 + n * 512 + u, packf(h));
  }
  __syncthreads();
}

// ================= phase B (R12-validated MFMA) =================
__device__ __forceinline__ void dev_phaseB(
    int gang, int gidx, int tid, int rp, int wp, float* bred,
    const unsigned short* __restrict__ W2H, const unsigned short* __restrict__ W2L,
    const float* __restrict__ B2,
    const unsigned* __restrict__ H1P, unsigned* __restrict__ H2P,
    float* __restrict__ C2)
{
  const int wid = tid >> 6, lane = tid & 63;
  const int l15 = lane & 15, lg = lane >> 4;
  const int mtB = gidx;
  if (tid < 256) {
    const int kb0 = wid * 160;
    int n = gang * 16 + l15;
    const unsigned* x1 = H1P + wp * 65536 + n * 512;
    const unsigned* x2 = H2P + rp * 16384 + n * 128;
    const unsigned short* whp = W2H + (size_t)(mtB * 16 + l15) * 640 + kb0 + lg * 8;
    const unsigned short* wlp = W2L + (size_t)(mtB * 16 + l15) * 640 + kb0 + lg * 8;
    f32x4 a0 = {0.0f, 0.0f, 0.0f, 0.0f};
    f32x4 a1 = {0.0f, 0.0f, 0.0f, 0.0f};
    f32x4 a2 = {0.0f, 0.0f, 0.0f, 0.0f};
#pragma unroll
    for (int ks = 0; ks < 5; ks++) {
      int kb = kb0 + ks * 32;
      unsigned parr[8];
      const unsigned* src = (kb < 512) ? (x1 + kb + lg * 8) : (x2 + (kb - 512) + lg * 8);
#pragma unroll
      for (int j = 0; j < 8; j++) parr[j] = aload(src + j);
      bf16x8 xh_, xl_;
      unpack8(parr, xh_, xl_);
      bf16x8 wh_ = *(const bf16x8*)(whp + ks * 32);
      bf16x8 wl_ = *(const bf16x8*)(wlp + ks * 32);
      a0 = __builtin_amdgcn_mfma_f32_16x16x32_bf16(wh_, xh_, a0, 0, 0, 0);
      a1 = __builtin_amdgcn_mfma_f32_16x16x32_bf16(wl_, xh_, a1, 0, 0, 0);
      a2 = __builtin_amdgcn_mfma_f32_16x16x32_bf16(wh_, xl_, a2, 0, 0, 0);
    }
    f32x4 acc = a0 + a1;
    acc = acc + a2;
#pragma unroll
    for (int q = 0; q < 4; q++) bred[q * 256 + wid * 64 + lane] = acc[q];
  }
  __syncthreads();
  if (tid < 64) {
    f32x4 b2v = *(const f32x4*)(B2 + mtB * 16 + lg * 4);
    float g0 = bred[lane]       + bred[64 + lane]  + bred[128 + lane] + bred[192 + lane] + b2v[0];
    float g1 = bred[256 + lane] + bred[320 + lane] + bred[384 + lane] + bred[448 + lane] + b2v[1];
    float g2 = bred[512 + lane] + bred[576 + lane] + bred[640 + lane] + bred[704 + lane] + b2v[2];
    float g3 = bred[768 + lane] + bred[832 + lane] + bred[896 + lane] + bred[960 + lane] + b2v[3];
    int n = gang * 16 + l15;
    int u = mtB * 4 + lg;
    float c = sigf(g1) * C2[u * 128 + n] + sigf(g0) * tanhf(g2);
    float h = sigf(g3) * tanhf(c);
    C2[u * 128 + n] = c;
    astore(H2P + wp * 16384 + n * 128 + u, packf(h));
  }
  __syncthreads();
}

// ================= phase C (R15-validated: fixed-shift softmax, shfl sums) =======
template <int BF16KV>
__device__ __forceinline__ void dev_phaseC(
    int n, int tid, int len, int t, int wp,
    float* cred, float* es, float* h2s, float* ctxs, float* pr, float* sred,
    const float* __restrict__ key, const float* __restrict__ values,
    const unsigned short* __restrict__ KB, const unsigned short* __restrict__ VB,
    const unsigned* __restrict__ H2P, const float* __restrict__ WoT,
    const float* __restrict__ bout, unsigned* __restrict__ CTXP,
    float* __restrict__ out)
{
  const int wid = tid >> 6, lane = tid & 63;
  if (tid < 128) h2s[tid] = unpackf(aload(H2P + wp * 16384 + n * 128 + tid));
  __syncthreads();
  float ls = 0.0f;
  if (tid < len) {
    float acc = 0.0f;
    if (BF16KV) {
      const u16x8* kr = (const u16x8*)(KB + ((size_t)tid * 128 + n) * 128);
#pragma unroll 4
      for (int k = 0; k < 16; k++) {
        u16x8 kv = kr[k];
#pragma unroll
        for (int j = 0; j < 8; j++) acc += b2f(kv[j]) * h2s[k * 8 + j];
      }
    } else {
      const float4* kr = (const float4*)(key + ((size_t)tid * 128 + n) * 128);
#pragma unroll 8
      for (int k = 0; k < 32; k++) {
        float4 kv = kr[k];
        acc += kv.x * h2s[4 * k] + kv.y * h2s[4 * k + 1] + kv.z * h2s[4 * k + 2] + kv.w * h2s[4 * k + 3];
      }
    }
    float p = expf(acc - 20.0f);   // fixed shift: exact softmax (shift-invariant)
    es[tid] = p;
    ls = p;
  }
  ls += __shfl_xor(ls, 32); ls += __shfl_xor(ls, 16); ls += __shfl_xor(ls, 8);
  ls += __shfl_xor(ls, 4);  ls += __shfl_xor(ls, 2);  ls += __shfl_xor(ls, 1);
  if (lane == 0) sred[wid] = ls;
  __syncthreads();
  float S = 0.0f;
#pragma unroll
  for (int w = 0; w < 16; w++) S += sred[w];
  {
    int v4 = (tid & 31) * 4, tp = tid >> 5;
    float ax = 0.0f, ay = 0.0f, az = 0.0f, aw = 0.0f;
    if (BF16KV) {
#pragma unroll 2
      for (int tt = tp; tt < len; tt += 32) {
        float p = es[tt];
        const unsigned* w = (const unsigned*)(VB + ((size_t)tt * 128 + n) * 128 + v4);
        unsigned w0 = w[0], w1 = w[1];
        ax += p * b2f((unsigned short)(w0 & 0xffffu));
        ay += p * b2f((unsigned short)(w0 >> 16));
        az += p * b2f((unsigned short)(w1 & 0xffffu));
        aw += p * b2f((unsigned short)(w1 >> 16));
      }
    } else {
#pragma unroll 2
      for (int tt = tp; tt < len; tt += 32) {
        float p = es[tt];
        const float4 vv = *(const float4*)(values + ((size_t)tt * 128 + n) * 128 + v4);
        ax += p * vv.x; ay += p * vv.y; az += p * vv.z; aw += p * vv.w;
      }
    }
    float4 a4 = {ax, ay, az, aw};
    *(float4*)&cred[tp * 132 + v4] = a4;
  }
  __syncthreads();
  if (tid < 128) {
    float s4 = 0.0f;
#pragma unroll 8
    for (int tp2 = 0; tp2 < 32; tp2++) s4 += cred[tp2 * 132 + tid];
    float cv = s4 / S;
    ctxs[tid] = cv;
    astore(CTXP + n * 128 + tid, packf(cv));
  }
  __syncthreads();
  if (tid < 68) {
    int vv = tid % 34, part = tid / 34;
    const float* src = part ? ctxs : h2s;
    const float* wcol = WoT + (part ? 128 * 34 : 0);
    float a = 0.0f;
#pragma unroll 8
    for (int k2 = 0; k2 < 128; k2++) a += src[k2] * wcol[k2 * 34 + vv];
    pr[tid] = a;
  }
  __syncthreads();
  if (tid < 34) {
    out[(size_t)n * (LDEC * VOCD) + t * VOCD + tid] = bout[tid] + pr[tid] + pr[34 + tid];
  }
  __syncthreads();
}

// ---------------- standalone fallback kernels (R15) ----------------
__global__ void __launch_bounds__(1024, 1) kA(
    const unsigned short* __restrict__ W1H, const unsigned short* __restrict__ W1L,
    const float* __restrict__ EG, const int* __restrict__ text,
    const unsigned* __restrict__ CTXP, unsigned* __restrict__ H1P,
    float* __restrict__ C1, int t, int rp, int wp)
{
  __shared__ unsigned xshA[16 * XSTR];
  __shared__ float bred[4096];
  const int gang = blockIdx.x >> 5, gidx = blockIdx.x & 31;
  stage_h1(gang, threadIdx.x, rp, xshA, H1P);
  stage_ctx(gang, threadIdx.x, xshA, CTXP);
  __syncthreads();
  A_compute(gang, gidx, threadIdx.x, t, wp, xshA, bred, W1H, W1L, EG, text, H1P, C1);
}
__global__ void __launch_bounds__(256) kB(
    const unsigned short* __restrict__ W2H, const unsigned short* __restrict__ W2L,
    const float* __restrict__ B2, const unsigned* __restrict__ H1P,
    unsigned* __restrict__ H2P, float* __restrict__ C2, int rp, int wp)
{
  __shared__ float bred[1024];
  dev_phaseB(blockIdx.x >> 5, blockIdx.x & 31, threadIdx.x, rp, wp, bred,
             W2H, W2L, B2, H1P, H2P, C2);
}
template <int BF16KV>
__global__ void __launch_bounds__(1024, 1) kC(
    const float* __restrict__ key, const float* __restrict__ values,
    const unsigned short* __restrict__ KB, const unsigned short* __restrict__ VB,
    const int* __restrict__ lens, const unsigned* __restrict__ H2P,
    const float* __restrict__ WoT, const float* __restrict__ bout,
    unsigned* __restrict__ CTXP, float* __restrict__ out, int t, int wp)
{
  __shared__ float cred[4224];
  __shared__ float es[512];
  __shared__ float h2s[128];
  __shared__ float ctxs[128];
  __shared__ float pr[68];
  __shared__ float sred[16];
  int n = blockIdx.x;
  dev_phaseC<BF16KV>(n, threadIdx.x, lens[n], t, wp, cred, es, h2s, ctxs, pr, sred,
                     key, values, KB, VB, H2P, WoT, bout, CTXP, out);
}

// ---------------- persistent gang kernel: slot-flag sync (no RMW) ----------------
template <int BF16KV>
__global__ void __launch_bounds__(1024, 1) decoder_coop(
    const float* __restrict__ key, const float* __restrict__ values,
    const unsigned short* __restrict__ KB, const unsigned short* __restrict__ VB,
    const int* __restrict__ lens, const int* __restrict__ text,
    const float* __restrict__ EG, const float* __restrict__ B2,
    const float* __restrict__ WoT, const float* __restrict__ bout,
    const unsigned short* __restrict__ W1H, const unsigned short* __restrict__ W1L,
    const unsigned short* __restrict__ W2H, const unsigned short* __restrict__ W2L,
    unsigned* __restrict__ CTXP, unsigned* __restrict__ H1P,
    unsigned* __restrict__ H2P, float* __restrict__ C1, float* __restrict__ C2,
    unsigned* __restrict__ FLG, float* __restrict__ out)
{
  __shared__ unsigned xshA[16 * XSTR];
  __shared__ float bred[4096];
  __shared__ float cred[4224];
  __shared__ float es[512];
  __shared__ float h2s[128];
  __shared__ float ctxs[128];
  __shared__ float pr[68];
  __shared__ float sred[16];
  __shared__ unsigned deadsh;

  const int bid = blockIdx.x, tid = threadIdx.x;
  const int gang = bid >> 5, gidx = bid & 31;
  // slot layout (words): 16-word (64B) stride per slot
  unsigned* sA = FLG + gang * 512;            // 32 slots
  unsigned* sB = FLG + 4096 + gang * 512;     // 32 slots
  unsigned* sC = FLG + 8192 + gang * 256;     // 16 slots
  const int cn = gang * 16 + gidx;
  const int clen = (gidx < 16) ? lens[cn] : 0;

  unsigned budget = SPIN_MAX;
  if (tid == 0) deadsh = 0u;

  // pre-stage h1(-1) (buffer 1, zeroed) for t=0
  stage_h1(gang, tid, 1, xshA, H1P);
  __syncthreads();

  for (int t = 0; t < LDEC; t++) {
    const int wp = t & 1, rp = (t + 1) & 1;
    const unsigned tv = (unsigned)(t + 1);

    // ---- A: ctx stage (critical path after C) + MFMA gates1 + LSTM1 ----
    stage_ctx(gang, tid, xshA, CTXP);
    __syncthreads();
    A_compute(gang, gidx, tid, t, wp, xshA, bred, W1H, W1L, EG, text, H1P, C1);
    if (tid == 0) { __builtin_amdgcn_s_waitcnt(0); astore(sA + gidx * 16, tv); }
    if (tid < 32) {                       // parallel per-slot wait, no RMW
      unsigned* s = sA + tid * 16;
      while (aload(s) < tv) {
        __builtin_amdgcn_s_sleep(1);
        if (--budget == 0) { deadsh = 1u; break; }
      }
    }
    __syncthreads();

    // ---- B ----
    dev_phaseB(gang, gidx, tid, rp, wp, bred, W2H, W2L, B2, H1P, H2P, C2);
    if (tid == 0) { __builtin_amdgcn_s_waitcnt(0); astore(sB + gidx * 16, tv); }

    // ---- prestage next step's h1 (overlaps B-completion + C; off critical path) ----
    stage_h1(gang, tid, wp, xshA, H1P);

    // ---- C (blocks gidx<16) ----
    if (gidx < 16) {
      if (tid < 32) {
        unsigned* s = sB + tid * 16;
        while (aload(s) < tv) {
          __builtin_amdgcn_s_sleep(1);
          if (--budget == 0) { deadsh = 1u; break; }
        }
      }
      __syncthreads();
      dev_phaseC<BF16KV>(cn, tid, clen, t, wp, cred, es, h2s, ctxs, pr, sred,
                         key, values, KB, VB, H2P, WoT, bout, CTXP, out);
      if (tid == 0) { __builtin_amdgcn_s_waitcnt(0); astore(sC + gidx * 16, tv); }
    }
    // ---- everyone waits for C before next step's A ----
    if (tid < 16) {
      unsigned* s = sC + tid * 16;
      while (aload(s) < tv) {
        __builtin_amdgcn_s_sleep(1);
        if (--budget == 0) { deadsh = 1u; break; }
      }
    }
    __syncthreads();
  }

  if (tid == 0 && deadsh) out[0] = 7.0e6f;
}

extern "C" void kernel_launch(void* const* d_in, const int* in_sizes, int n_in,
                              void* d_out, int out_size, void* d_ws, size_t ws_size,
                              hipStream_t stream) {
  const float* key    = (const float*)d_in[0];
  const float* values = (const float*)d_in[1];
  const int*   lens   = (const int*)d_in[2];
  const int*   text   = (const int*)d_in[3];
  const float* emb    = (const float*)d_in[4];
  const float* Wih1   = (const float*)d_in[5];
  const float* Whh1   = (const float*)d_in[6];
  const float* bih1   = (const float*)d_in[7];
  const float* bhh1   = (const float*)d_in[8];
  const float* Wih2   = (const float*)d_in[9];
  const float* Whh2   = (const float*)d_in[10];
  const float* bih2   = (const float*)d_in[11];
  const float* bhh2   = (const float*)d_in[12];
  const float* Wout   = (const float*)d_in[13];
  const float* bout   = (const float*)d_in[14];

  char* ws = (char*)d_ws;
  unsigned short* W1H = (unsigned short*)(ws + OFF_W1H);
  unsigned short* W1L = (unsigned short*)(ws + OFF_W1L);
  unsigned short* W2H = (unsigned short*)(ws + OFF_W2H);
  unsigned short* W2L = (unsigned short*)(ws + OFF_W2L);
  float* EG   = (float*)(ws + OFF_EG);
  float* B2   = (float*)(ws + OFF_B2);
  float* WoT  = (float*)(ws + OFF_WOT);
  unsigned* H1P  = (unsigned*)(ws + OFF_H1P);
  unsigned* H2P  = (unsigned*)(ws + OFF_H2P);
  unsigned* CTXP = (unsigned*)(ws + OFF_CTXP);
  float* C1   = (float*)(ws + OFF_C1);
  float* C2   = (float*)(ws + OFF_C2);
  unsigned* FLG = (unsigned*)(ws + OFF_FLG);
  unsigned short* KB = (unsigned short*)(ws + OFF_KB);
  unsigned short* VB = (unsigned short*)(ws + OFF_VB);
  float* out  = (float*)d_out;

  const bool use16 = (ws_size >= (size_t)WS_NEED);

  hipMemsetAsync(CTXP, 0, 65536, stream);
  hipMemsetAsync((char*)H1P + 262144, 0, 262144, stream);   // buf1: h1(-1)=0
  hipMemsetAsync((char*)H2P + 65536, 0, 65536, stream);     // buf1: h2(-1)=0
  hipMemsetAsync(C1,  0, 262144, stream);
  hipMemsetAsync(C2,  0, 65536, stream);
  hipMemsetAsync(FLG, 0, 49152, stream);

  pack_w1  <<<5120, 256, 0, stream>>>(Wih1, Whh1, W1H, W1L);
  pack_w2  <<<1280, 256, 0, stream>>>(Wih2, Whh2, W2H, W2L);
  pack_eg  <<<272,  256, 0, stream>>>(emb, Wih1, bih1, bhh1, EG);
  pack_misc<<<36,   256, 0, stream>>>(Wout, bih2, bhh2, WoT, B2);
  if (use16) pack_kv<<<32768, 256, 0, stream>>>(key, values, KB, VB);

  const void* coop_fn = use16 ? (const void*)decoder_coop<1>
                              : (const void*)decoder_coop<0>;

  int maxBlk = 0;
  hipError_t qerr = hipOccupancyMaxActiveBlocksPerMultiprocessor(
      &maxBlk, coop_fn, 1024, 0);
  bool coop_ok = (qerr == hipSuccess && maxBlk >= 1);

  if (coop_ok) {
    void* args[] = {
      (void*)&key, (void*)&values, (void*)&KB, (void*)&VB,
      (void*)&lens, (void*)&text,
      (void*)&EG, (void*)&B2, (void*)&WoT, (void*)&bout,
      (void*)&W1H, (void*)&W1L, (void*)&W2H, (void*)&W2L,
      (void*)&CTXP, (void*)&H1P, (void*)&H2P, (void*)&C1, (void*)&C2,
      (void*)&FLG, (void*)&out
    };
    hipError_t err = hipLaunchCooperativeKernel(coop_fn, dim3(256), dim3(1024),
                                                args, 0, stream);
    if (err == hipSuccess) return;
  }

  // fallback: multi-launch
  for (int t = 0; t < LDEC; t++) {
    const int wp = t & 1, rp = (t + 1) & 1;
    kA<<<256, 1024, 0, stream>>>(W1H, W1L, EG, text, CTXP, H1P, C1, t, rp, wp);
    kB<<<256, 256,  0, stream>>>(W2H, W2L, B2, H1P, H2P, C2, rp, wp);
    if (use16)
      kC<1><<<128, 1024, 0, stream>>>(key, values, KB, VB, lens, H2P, WoT, bout,
                                      CTXP, out, t, wp);
    else
      kC<0><<<128, 1024, 0, stream>>>(key, values, KB, VB, lens, H2P, WoT, bout,
                                      CTXP, out, t, wp);
  }
}

// Round 18
// 7853.251 us; speedup vs baseline: 1.8907x; 1.0028x over previous
//
#include <hip/hip_runtime.h>
#include <hip/hip_cooperative_groups.h>
#include <math.h>

#define LDEC 256
#define VOCD 34
#define SPIN_MAX 2000000u
#define XSTR 660   // LDS row stride (words): %32==20 -> 2-way bank aliasing (free)

typedef __attribute__((ext_vector_type(8))) short bf16x8;
typedef __attribute__((ext_vector_type(8))) unsigned short u16x8;
typedef __attribute__((ext_vector_type(4))) float f32x4;

// ---------------- workspace layout (byte offsets) ----------------
#define OFF_W1H  0u
#define OFF_W1L  2621440u
#define OFF_W2H  5242880u
#define OFF_W2L  5898240u
#define OFF_EG   6553600u
#define OFF_B2   6832128u
#define OFF_WOT  6834176u
#define OFF_H1P  6868992u    // u32 [2][128 n][512 k]
#define OFF_H2P  7393280u    // u32 [2][128 n][128 u]
#define OFF_CTXP 7524352u    // u32 [128 n][128 k]
#define OFF_C1   7589888u
#define OFF_C2   7852032u
#define OFF_FLG  7917568u    // slot flags: sA 8g*32, sB 8g*32, sC 8g*16; 64B stride
#define OFF_KB   7966720u    // bf16 [512 t][128 n][128 k]
#define OFF_VB   24743936u
#define WS_NEED  41521152u

__device__ __forceinline__ float sigf(float x) { return 1.0f / (1.0f + expf(-x)); }
__device__ __forceinline__ unsigned short f2b(float x) {
  unsigned int u = __float_as_uint(x);
  unsigned int r = (u + 0x7FFFu + ((u >> 16) & 1u)) >> 16;
  return (unsigned short)r;
}
__device__ __forceinline__ float b2f(unsigned short h) {
  return __uint_as_float(((unsigned int)h) << 16);
}
__device__ __forceinline__ unsigned packf(float x) {
  unsigned short hi = f2b(x);
  unsigned short lo = f2b(x - b2f(hi));
  return ((unsigned)hi << 16) | (unsigned)lo;
}
__device__ __forceinline__ float unpackf(unsigned p) {
  return b2f((unsigned short)(p >> 16)) + b2f((unsigned short)(p & 0xffffu));
}
__device__ __forceinline__ unsigned aload(const unsigned* p) {
  return __hip_atomic_load((unsigned*)p, __ATOMIC_RELAXED, __HIP_MEMORY_SCOPE_SYSTEM);
}
__device__ __forceinline__ void astore(unsigned* p, unsigned v) {
  __hip_atomic_store(p, v, __ATOMIC_RELAXED, __HIP_MEMORY_SCOPE_SYSTEM);
}
__device__ __forceinline__ void unpack8(const unsigned* p, bf16x8& xh, bf16x8& xl) {
#pragma unroll
  for (int j = 0; j < 8; j++) {
    unsigned v = p[j];
    xh[j] = (short)(v >> 16);
    xl[j] = (short)(v & 0xffffu);
  }
}

// ---------------- pack kernels ----------------
__global__ __launch_bounds__(256) void pack_w1(const float* __restrict__ Wih1,
                                               const float* __restrict__ Whh1,
                                               unsigned short* __restrict__ W1H,
                                               unsigned short* __restrict__ W1L) {
  int idx = blockIdx.x * 256 + threadIdx.x;
  int m = idx / 640, k = idx % 640;
  int u = m >> 2, q = m & 3;
  int g = q * 512 + u;
  float v = (k < 128) ? Wih1[g * 384 + 256 + k] : Whh1[g * 512 + (k - 128)];
  unsigned short hi = f2b(v);
  W1H[idx] = hi;
  W1L[idx] = f2b(v - b2f(hi));
}

__global__ __launch_bounds__(256) void pack_w2(const float* __restrict__ Wih2,
                                               const float* __restrict__ Whh2,
                                               unsigned short* __restrict__ W2H,
                                               unsigned short* __restrict__ W2L) {
  int idx = blockIdx.x * 256 + threadIdx.x;
  int m = idx / 640, k = idx % 640;
  int u = m >> 2, q = m & 3;
  int g = q * 128 + u;
  float v = (k < 512) ? Wih2[g * 512 + k] : Whh2[g * 128 + (k - 512)];
  unsigned short hi = f2b(v);
  W2H[idx] = hi;
  W2L[idx] = f2b(v - b2f(hi));
}

__global__ __launch_bounds__(256) void pack_eg(const float* __restrict__ emb,
                                               const float* __restrict__ Wih1,
                                               const float* __restrict__ bih1,
                                               const float* __restrict__ bhh1,
                                               float* __restrict__ EG) {
  int idx = blockIdx.x * 256 + threadIdx.x;
  int v = idx >> 11, m = idx & 2047;
  int u = m >> 2, q = m & 3;
  int g = q * 512 + u;
  float acc = bih1[g] + bhh1[g];
  const float* e = emb + v * 256;
  const float* w = Wih1 + g * 384;
  for (int k = 0; k < 256; k++) acc += e[k] * w[k];
  EG[idx] = acc;
}

__global__ __launch_bounds__(256) void pack_misc(const float* __restrict__ Wout,
                                                 const float* __restrict__ bih2,
                                                 const float* __restrict__ bhh2,
                                                 float* __restrict__ WoT,
                                                 float* __restrict__ B2) {
  int idx = blockIdx.x * 256 + threadIdx.x;
  if (idx < 8704) {
    int k = idx / 34, v = idx % 34;
    WoT[idx] = Wout[v * 256 + k];
  } else if (idx < 9216) {
    int m = idx - 8704;
    int u = m >> 2, q = m & 3;
    int g = q * 128 + u;
    B2[m] = bih2[g] + bhh2[g];
  }
}

__global__ __launch_bounds__(256) void pack_kv(const float* __restrict__ key,
                                               const float* __restrict__ values,
                                               unsigned short* __restrict__ KB,
                                               unsigned short* __restrict__ VB) {
  size_t idx = (size_t)blockIdx.x * 256 + threadIdx.x;
  KB[idx] = f2b(key[idx]);
  VB[idx] = f2b(values[idx]);
}

// ================= staging helpers (stride XSTR) =================
__device__ __forceinline__ void stage_h1(int gang, int tid, int rbuf,
                                         unsigned* xshA, const unsigned* __restrict__ H1P) {
  int kcol = tid & 15, nl = (tid >> 4) & 15, rep = tid >> 8;
  int n = gang * 16 + nl;
  const unsigned* h1p = H1P + rbuf * 65536 + n * 512;
#pragma unroll
  for (int j = 0; j < 10; j++) {
    int k = rep * 160 + j * 16 + kcol;
    if (k >= 128) xshA[nl * XSTR + k] = aload(h1p + (k - 128));
  }
}
__device__ __forceinline__ void stage_ctx(int gang, int tid,
                                          unsigned* xshA, const unsigned* __restrict__ CTXP) {
  int kcol = tid & 15, nl = (tid >> 4) & 15, rep = tid >> 8;
  int n = gang * 16 + nl;
  if (rep == 0) {
#pragma unroll
    for (int j = 0; j < 8; j++) {
      int k = j * 16 + kcol;
      xshA[nl * XSTR + k] = aload(CTXP + n * 128 + k);
    }
  }
}

// ================= phase A (R12-validated MFMA; XCD-partitioned m-tiles) =========
__device__ __forceinline__ void A_compute(
    int gang, int gidx, int tid, int t, int wp,
    const unsigned* __restrict__ xshA, float* bred,
    const unsigned short* __restrict__ W1H, const unsigned short* __restrict__ W1L,
    const float* __restrict__ EG, const int* __restrict__ text,
    unsigned* __restrict__ H1P, float* __restrict__ C1)
{
  const int wid = tid >> 6, lane = tid & 63;
  const int l15 = lane & 15, lg = lane >> 4;
  const int gr = wid >> 2, gwid = wid & 3;
  const int kb0 = gwid * 160;
  // XCD partition: blocks with gidx%8==x only touch m-tiles [x*16, x*16+16)
  const int mt = (gidx & 7) * 16 + (gidx >> 3) * 4 + gr;

  {
    const unsigned short* whp = W1H + (size_t)(mt * 16 + l15) * 640 + kb0 + lg * 8;
    const unsigned short* wlp = W1L + (size_t)(mt * 16 + l15) * 640 + kb0 + lg * 8;
    const unsigned* xrow = xshA + l15 * XSTR + kb0 + lg * 8;
    f32x4 a0 = {0.0f, 0.0f, 0.0f, 0.0f};
    f32x4 a1 = {0.0f, 0.0f, 0.0f, 0.0f};
    f32x4 a2 = {0.0f, 0.0f, 0.0f, 0.0f};
#pragma unroll
    for (int ks = 0; ks < 5; ks++) {
      unsigned parr[8];
      *(uint4*)parr       = *(const uint4*)(xrow + ks * 32);
      *(uint4*)(parr + 4) = *(const uint4*)(xrow + ks * 32 + 4);
      bf16x8 xh_, xl_;
      unpack8(parr, xh_, xl_);
      bf16x8 wh_ = *(const bf16x8*)(whp + ks * 32);
      bf16x8 wl_ = *(const bf16x8*)(wlp + ks * 32);
      a0 = __builtin_amdgcn_mfma_f32_16x16x32_bf16(wh_, xh_, a0, 0, 0, 0);
      a1 = __builtin_amdgcn_mfma_f32_16x16x32_bf16(wl_, xh_, a1, 0, 0, 0);
      a2 = __builtin_amdgcn_mfma_f32_16x16x32_bf16(wh_, xl_, a2, 0, 0, 0);
    }
    f32x4 acc = a0 + a1;
    acc = acc + a2;
#pragma unroll
    for (int q = 0; q < 4; q++) bred[gr * 1024 + q * 256 + gwid * 64 + lane] = acc[q];
  }
  __syncthreads();

  if (gwid == 0) {
    const float* br = bred + gr * 1024;
    int n = gang * 16 + l15;
    int tok = text[n * LDEC + t];
    f32x4 egv = *(const f32x4*)(EG + (size_t)tok * 2048 + mt * 16 + lg * 4);
    float g0 = br[lane]       + br[64 + lane]  + br[128 + lane] + br[192 + lane] + egv[0];
    float g1 = br[256 + lane] + br[320 + lane] + br[384 + lane] + br[448 + lane] + egv[1];
    float g2 = br[512 + lane] + br[576 + lane] + br[640 + lane] + br[704 + lane] + egv[2];
    float g3 = br[768 + lane] + br[832 + lane] + br[896 + lane] + br[960 + lane] + egv[3];
    float ig = sigf(g0), fg = sigf(g1), gg = tanhf(g2), og = sigf(g3);
    int u = mt * 4 + lg;
    float c = fg * C1[u * 128 + n] + ig * gg;
    float h = og * tanhf(c);
    C1[u * 128 + n] = c;
    astore(H1P + wp * 65536 + n * 512 + u, packf(h));
  }
  __syncthreads();
}

// ================= phase B (R12-validated MFMA; XCD-partitioned m-tiles) =========
__device__ __forceinline__ void dev_phaseB(
    int gang, int gidx, int tid, int rp, int wp, float* bred,
    const unsigned short* __restrict__ W2H, const unsigned short* __restrict__ W2L,
    const float* __restrict__ B2,
    const unsigned* __restrict__ H1P, unsigned* __restrict__ H2P,
    float* __restrict__ C2)
{
  const int wid = tid >> 6, lane = tid & 63;
  const int l15 = lane & 15, lg = lane >> 4;
  const int mtB = (gidx & 7) * 4 + (gidx >> 3);   // XCD partition
  if (tid < 256) {
    const int kb0 = wid * 160;
    int n = gang * 16 + l15;
    const unsigned* x1 = H1P + wp * 65536 + n * 512;
    const unsigned* x2 = H2P + rp * 16384 + n * 128;
    const unsigned short* whp = W2H + (size_t)(mtB * 16 + l15) * 640 + kb0 + lg * 8;
    const unsigned short* wlp = W2L + (size_t)(mtB * 16 + l15) * 640 + kb0 + lg * 8;
    f32x4 a0 = {0.0f, 0.0f, 0.0f, 0.0f};
    f32x4 a1 = {0.0f, 0.0f, 0.0f, 0.0f};
    f32x4 a2 = {0.0f, 0.0f, 0.0f, 0.0f};
#pragma unroll
    for (int ks = 0; ks < 5; ks++) {
      int kb = kb0 + ks * 32;
      unsigned parr[8];
      const unsigned* src = (kb < 512) ? (x1 + kb + lg * 8) : (x2 + (kb - 512) + lg * 8);
#pragma unroll
      for (int j = 0; j < 8; j++) parr[j] = aload(src + j);
      bf16x8 xh_, xl_;
      unpack8(parr, xh_, xl_);
      bf16x8 wh_ = *(const bf16x8*)(whp + ks * 32);
      bf16x8 wl_ = *(const bf16x8*)(wlp + ks * 32);
      a0 = __builtin_amdgcn_mfma_f32_16x16x32_bf16(wh_, xh_, a0, 0, 0, 0);
      a1 = __builtin_amdgcn_mfma_f32_16x16x32_bf16(wl_, xh_, a1, 0, 0, 0);
      a2 = __builtin_amdgcn_mfma_f32_16x16x32_bf16(wh_, xl_, a2, 0, 0, 0);
    }
    f32x4 acc = a0 + a1;
    acc = acc + a2;
#pragma unroll
    for (int q = 0; q < 4; q++) bred[q * 256 + wid * 64 + lane] = acc[q];
  }
  __syncthreads();
  if (tid < 64) {
    f32x4 b2v = *(const f32x4*)(B2 + mtB * 16 + lg * 4);
    float g0 = bred[lane]       + bred[64 + lane]  + bred[128 + lane] + bred[192 + lane] + b2v[0];
    float g1 = bred[256 + lane] + bred[320 + lane] + bred[384 + lane] + bred[448 + lane] + b2v[1];
    float g2 = bred[512 + lane] + bred[576 + lane] + bred[640 + lane] + bred[704 + lane] + b2v[2];
    float g3 = bred[768 + lane] + bred[832 + lane] + bred[896 + lane] + bred[960 + lane] + b2v[3];
    int n = gang * 16 + l15;
    int u = mtB * 4 + lg;
    float c = sigf(g1) * C2[u * 128 + n] + sigf(g0) * tanhf(g2);
    float h = sigf(g3) * tanhf(c);
    C2[u * 128 + n] = c;
    astore(H2P + wp * 16384 + n * 128 + u, packf(h));
  }
  __syncthreads();
}

// ===== phase C (R15-validated; early-fC: arrive right after ctx-write barrier) ====
template <int BF16KV>
__device__ __forceinline__ void dev_phaseC(
    int n, int tid, int len, int t, int wp,
    float* cred, float* es, float* h2s, float* ctxs, float* pr, float* sred,
    const float* __restrict__ key, const float* __restrict__ values,
    const unsigned short* __restrict__ KB, const unsigned short* __restrict__ VB,
    const unsigned* __restrict__ H2P, const float* __restrict__ WoT,
    const float* __restrict__ bout, unsigned* __restrict__ CTXP,
    float* __restrict__ out, unsigned* sCslot, unsigned tv)
{
  const int wid = tid >> 6, lane = tid & 63;
  if (tid < 128) h2s[tid] = unpackf(aload(H2P + wp * 16384 + n * 128 + tid));
  __syncthreads();
  float ls = 0.0f;
  if (tid < len) {
    float acc = 0.0f;
    if (BF16KV) {
      const u16x8* kr = (const u16x8*)(KB + ((size_t)tid * 128 + n) * 128);
#pragma unroll 4
      for (int k = 0; k < 16; k++) {
        u16x8 kv = kr[k];
#pragma unroll
        for (int j = 0; j < 8; j++) acc += b2f(kv[j]) * h2s[k * 8 + j];
      }
    } else {
      const float4* kr = (const float4*)(key + ((size_t)tid * 128 + n) * 128);
#pragma unroll 8
      for (int k = 0; k < 32; k++) {
        float4 kv = kr[k];
        acc += kv.x * h2s[4 * k] + kv.y * h2s[4 * k + 1] + kv.z * h2s[4 * k + 2] + kv.w * h2s[4 * k + 3];
      }
    }
    float p = expf(acc - 20.0f);   // fixed shift: exact softmax (shift-invariant)
    es[tid] = p;
    ls = p;
  }
  ls += __shfl_xor(ls, 32); ls += __shfl_xor(ls, 16); ls += __shfl_xor(ls, 8);
  ls += __shfl_xor(ls, 4);  ls += __shfl_xor(ls, 2);  ls += __shfl_xor(ls, 1);
  if (lane == 0) sred[wid] = ls;
  __syncthreads();
  float S = 0.0f;
#pragma unroll
  for (int w = 0; w < 16; w++) S += sred[w];
  {
    int v4 = (tid & 31) * 4, tp = tid >> 5;
    float ax = 0.0f, ay = 0.0f, az = 0.0f, aw = 0.0f;
    if (BF16KV) {
#pragma unroll 2
      for (int tt = tp; tt < len; tt += 32) {
        float p = es[tt];
        const unsigned* w = (const unsigned*)(VB + ((size_t)tt * 128 + n) * 128 + v4);
        unsigned w0 = w[0], w1 = w[1];
        ax += p * b2f((unsigned short)(w0 & 0xffffu));
        ay += p * b2f((unsigned short)(w0 >> 16));
        az += p * b2f((unsigned short)(w1 & 0xffffu));
        aw += p * b2f((unsigned short)(w1 >> 16));
      }
    } else {
#pragma unroll 2
      for (int tt = tp; tt < len; tt += 32) {
        float p = es[tt];
        const float4 vv = *(const float4*)(values + ((size_t)tt * 128 + n) * 128 + v4);
        ax += p * vv.x; ay += p * vv.y; az += p * vv.z; aw += p * vv.w;
      }
    }
    float4 a4 = {ax, ay, az, aw};
    *(float4*)&cred[tp * 132 + v4] = a4;
  }
  __syncthreads();
  if (tid < 128) {
    float s4 = 0.0f;
#pragma unroll 8
    for (int tp2 = 0; tp2 < 32; tp2++) s4 += cred[tp2 * 132 + tid];
    float cv = s4 / S;
    ctxs[tid] = cv;
    astore(CTXP + n * 128 + tid, packf(cv));
  }
  __syncthreads();   // drains all waves' ctx stores (compiler waitcnt before barrier)
  if (sCslot && tid == 0) astore(sCslot, tv);   // EARLY fC: ctx visible; proj off path
  if (tid < 68) {
    int vv = tid % 34, part = tid / 34;
    const float* src = part ? ctxs : h2s;
    const float* wcol = WoT + (part ? 128 * 34 : 0);
    float a = 0.0f;
#pragma unroll 8
    for (int k2 = 0; k2 < 128; k2++) a += src[k2] * wcol[k2 * 34 + vv];
    pr[tid] = a;
  }
  __syncthreads();
  if (tid < 34) {
    out[(size_t)n * (LDEC * VOCD) + t * VOCD + tid] = bout[tid] + pr[tid] + pr[34 + tid];
  }
  __syncthreads();
}

// ---------------- standalone fallback kernels ----------------
__global__ void __launch_bounds__(1024, 1) kA(
    const unsigned short* __restrict__ W1H, const unsigned short* __restrict__ W1L,
    const float* __restrict__ EG, const int* __restrict__ text,
    const unsigned* __restrict__ CTXP, unsigned* __restrict__ H1P,
    float* __restrict__ C1, int t, int rp, int wp)
{
  __shared__ unsigned xshA[16 * XSTR];
  __shared__ float bred[4096];
  const int gang = blockIdx.x >> 5, gidx = blockIdx.x & 31;
  stage_h1(gang, threadIdx.x, rp, xshA, H1P);
  stage_ctx(gang, threadIdx.x, xshA, CTXP);
  __syncthreads();
  A_compute(gang, gidx, threadIdx.x, t, wp, xshA, bred, W1H, W1L, EG, text, H1P, C1);
}
__global__ void __launch_bounds__(256) kB(
    const unsigned short* __restrict__ W2H, const unsigned short* __restrict__ W2L,
    const float* __restrict__ B2, const unsigned* __restrict__ H1P,
    unsigned* __restrict__ H2P, float* __restrict__ C2, int rp, int wp)
{
  __shared__ float bred[1024];
  dev_phaseB(blockIdx.x >> 5, blockIdx.x & 31, threadIdx.x, rp, wp, bred,
             W2H, W2L, B2, H1P, H2P, C2);
}
template <int BF16KV>
__global__ void __launch_bounds__(1024, 1) kC(
    const float* __restrict__ key, const float* __restrict__ values,
    const unsigned short* __restrict__ KB, const unsigned short* __restrict__ VB,
    const int* __restrict__ lens, const unsigned* __restrict__ H2P,
    const float* __restrict__ WoT, const float* __restrict__ bout,
    unsigned* __restrict__ CTXP, float* __restrict__ out, int t, int wp)
{
  __shared__ float cred[4224];
  __shared__ float es[512];
  __shared__ float h2s[128];
  __shared__ float ctxs[128];
  __shared__ float pr[68];
  __shared__ float sred[16];
  int n = blockIdx.x;
  dev_phaseC<BF16KV>(n, threadIdx.x, lens[n], t, wp, cred, es, h2s, ctxs, pr, sred,
                     key, values, KB, VB, H2P, WoT, bout, CTXP, out,
                     (unsigned*)0, 0u);
}

// ---------------- persistent gang kernel: slot-flag sync, spin-only polls --------
template <int BF16KV>
__global__ void __launch_bounds__(1024, 1) decoder_coop(
    const float* __restrict__ key, const float* __restrict__ values,
    const unsigned short* __restrict__ KB, const unsigned short* __restrict__ VB,
    const int* __restrict__ lens, const int* __restrict__ text,
    const float* __restrict__ EG, const float* __restrict__ B2,
    const float* __restrict__ WoT, const float* __restrict__ bout,
    const unsigned short* __restrict__ W1H, const unsigned short* __restrict__ W1L,
    const unsigned short* __restrict__ W2H, const unsigned short* __restrict__ W2L,
    unsigned* __restrict__ CTXP, unsigned* __restrict__ H1P,
    unsigned* __restrict__ H2P, float* __restrict__ C1, float* __restrict__ C2,
    unsigned* __restrict__ FLG, float* __restrict__ out)
{
  __shared__ unsigned xshA[16 * XSTR];
  __shared__ float bred[4096];
  __shared__ float cred[4224];
  __shared__ float es[512];
  __shared__ float h2s[128];
  __shared__ float ctxs[128];
  __shared__ float pr[68];
  __shared__ float sred[16];
  __shared__ unsigned deadsh;

  const int bid = blockIdx.x, tid = threadIdx.x;
  const int gang = bid >> 5, gidx = bid & 31;
  unsigned* sA = FLG + gang * 512;            // 32 slots x 16 words
  unsigned* sB = FLG + 4096 + gang * 512;     // 32 slots
  unsigned* sC = FLG + 8192 + gang * 256;     // 16 slots
  const int cn = gang * 16 + gidx;
  const int clen = (gidx < 16) ? lens[cn] : 0;

  unsigned budget = SPIN_MAX;
  if (tid == 0) deadsh = 0u;

  // pre-stage h1(-1) (buffer 1, zeroed) for t=0
  stage_h1(gang, tid, 1, xshA, H1P);
  __syncthreads();

  for (int t = 0; t < LDEC; t++) {
    const int wp = t & 1, rp = (t + 1) & 1;
    const unsigned tv = (unsigned)(t + 1);

    // ---- A: ctx stage (critical path after C) + MFMA gates1 + LSTM1 ----
    stage_ctx(gang, tid, xshA, CTXP);
    __syncthreads();
    A_compute(gang, gidx, tid, t, wp, xshA, bred, W1H, W1L, EG, text, H1P, C1);
    if (tid == 0) astore(sA + gidx * 16, tv);   // A_compute ends with __syncthreads (drained)
    if (tid < 32) {                              // spin-only parallel per-slot wait
      unsigned* s = sA + tid * 16;
      while (aload(s) < tv) {
        if (--budget == 0) { deadsh = 1u; break; }
      }
    }
    __syncthreads();

    // ---- B ----
    dev_phaseB(gang, gidx, tid, rp, wp, bred, W2H, W2L, B2, H1P, H2P, C2);
    if (tid == 0) astore(sB + gidx * 16, tv);

    // ---- prestage next step's h1 (overlaps B-completion + C) ----
    stage_h1(gang, tid, wp, xshA, H1P);

    // ---- C (blocks gidx<16) ----
    if (gidx < 16) {
      if (tid < 32) {
        unsigned* s = sB + tid * 16;
        while (aload(s) < tv) {
          if (--budget == 0) { deadsh = 1u; break; }
        }
      }
      __syncthreads();
      dev_phaseC<BF16KV>(cn, tid, clen, t, wp, cred, es, h2s, ctxs, pr, sred,
                         key, values, KB, VB, H2P, WoT, bout, CTXP, out,
                         sC + gidx * 16, tv);
    }
    // ---- everyone waits for C's ctx before next step's A ----
    if (tid < 16) {
      unsigned* s = sC + tid * 16;
      while (aload(s) < tv) {
        if (--budget == 0) { deadsh = 1u; break; }
      }
    }
    __syncthreads();
  }

  if (tid == 0 && deadsh) out[0] = 7.0e6f;
}

extern "C" void kernel_launch(void* const* d_in, const int* in_sizes, int n_in,
                              void* d_out, int out_size, void* d_ws, size_t ws_size,
                              hipStream_t stream) {
  const float* key    = (const float*)d_in[0];
  const float* values = (const float*)d_in[1];
  const int*   lens   = (const int*)d_in[2];
  const int*   text   = (const int*)d_in[3];
  const float* emb    = (const float*)d_in[4];
  const float* Wih1   = (const float*)d_in[5];
  const float* Whh1   = (const float*)d_in[6];
  const float* bih1   = (const float*)d_in[7];
  const float* bhh1   = (const float*)d_in[8];
  const float* Wih2   = (const float*)d_in[9];
  const float* Whh2   = (const float*)d_in[10];
  const float* bih2   = (const float*)d_in[11];
  const float* bhh2   = (const float*)d_in[12];
  const float* Wout   = (const float*)d_in[13];
  const float* bout   = (const float*)d_in[14];

  char* ws = (char*)d_ws;
  unsigned short* W1H = (unsigned short*)(ws + OFF_W1H);
  unsigned short* W1L = (unsigned short*)(ws + OFF_W1L);
  unsigned short* W2H = (unsigned short*)(ws + OFF_W2H);
  unsigned short* W2L = (unsigned short*)(ws + OFF_W2L);
  float* EG   = (float*)(ws + OFF_EG);
  float* B2   = (float*)(ws + OFF_B2);
  float* WoT  = (float*)(ws + OFF_WOT);
  unsigned* H1P  = (unsigned*)(ws + OFF_H1P);
  unsigned* H2P  = (unsigned*)(ws + OFF_H2P);
  unsigned* CTXP = (unsigned*)(ws + OFF_CTXP);
  float* C1   = (float*)(ws + OFF_C1);
  float* C2   = (float*)(ws + OFF_C2);
  unsigned* FLG = (unsigned*)(ws + OFF_FLG);
  unsigned short* KB = (unsigned short*)(ws + OFF_KB);
  unsigned short* VB = (unsigned short*)(ws + OFF_VB);
  float* out  = (float*)d_out;

  const bool use16 = (ws_size >= (size_t)WS_NEED);

  hipMemsetAsync(CTXP, 0, 65536, stream);
  hipMemsetAsync((char*)H1P + 262144, 0, 262144, stream);   // buf1: h1(-1)=0
  hipMemsetAsync((char*)H2P + 65536, 0, 65536, stream);     // buf1: h2(-1)=0
  hipMemsetAsync(C1,  0, 262144, stream);
  hipMemsetAsync(C2,  0, 65536, stream);
  hipMemsetAsync(FLG, 0, 49152, stream);

  pack_w1  <<<5120, 256, 0, stream>>>(Wih1, Whh1, W1H, W1L);
  pack_w2  <<<1280, 256, 0, stream>>>(Wih2, Whh2, W2H, W2L);
  pack_eg  <<<272,  256, 0, stream>>>(emb, Wih1, bih1, bhh1, EG);
  pack_misc<<<36,   256, 0, stream>>>(Wout, bih2, bhh2, WoT, B2);
  if (use16) pack_kv<<<32768, 256, 0, stream>>>(key, values, KB, VB);

  const void* coop_fn = use16 ? (const void*)decoder_coop<1>
                              : (const void*)decoder_coop<0>;

  int maxBlk = 0;
  hipError_t qerr = hipOccupancyMaxActiveBlocksPerMultiprocessor(
      &maxBlk, coop_fn, 1024, 0);
  bool coop_ok = (qerr == hipSuccess && maxBlk >= 1);

  if (coop_ok) {
    void* args[] = {
      (void*)&key, (void*)&values, (void*)&KB, (void*)&VB,
      (void*)&lens, (void*)&text,
      (void*)&EG, (void*)&B2, (void*)&WoT, (void*)&bout,
      (void*)&W1H, (void*)&W1L, (void*)&W2H, (void*)&W2L,
      (void*)&CTXP, (void*)&H1P, (void*)&H2P, (void*)&C1, (void*)&C2,
      (void*)&FLG, (void*)&out
    };
    hipError_t err = hipLaunchCooperativeKernel(coop_fn, dim3(256), dim3(1024),
                                                args, 0, stream);
    if (err == hipSuccess) return;
  }

  // fallback: multi-launch
  for (int t = 0; t < LDEC; t++) {
    const int wp = t & 1, rp = (t + 1) & 1;
    kA<<<256, 1024, 0, stream>>>(W1H, W1L, EG, text, CTXP, H1P, C1, t, rp, wp);
    kB<<<256, 256,  0, stream>>>(W2H, W2L, B2, H1P, H2P, C2, rp, wp);
    if (use16)
      kC<1><<<128, 1024, 0, stream>>>(key, values, KB, VB, lens, H2P, WoT, bout,
                                      CTXP, out, t, wp);
    else
      kC<0><<<128, 1024, 0, stream>>>(key, values, KB, VB, lens, H2P, WoT, bout,
                                      CTXP, out, t, wp);
  }
}